// Round 1
// baseline (807.113 us; speedup 1.0000x reference)
//
#include <hip/hip_runtime.h>

#define BATCH 32768
#define SEQ 30
#define INP 13
#define HID 128
#define ROWS 16
#define NBLK (BATCH/ROWS)        // 2048 blocks
#define THREADS 512              // 8 waves
#define H1PITCH 136              // shorts per row (128 + 8 pad -> 2-way-free LDS banks)
#define H1SLOT (ROWS*H1PITCH)    // 2176 shorts per timestep tile
#define LDS_SHORTS (SEQ*H1SLOT + 2*H1SLOT)
#define LDS_BYTES (LDS_SHORTS*2) // 139,264 B

typedef float f32x4  __attribute__((ext_vector_type(4)));
typedef short bf16x8 __attribute__((ext_vector_type(8)));

__device__ inline unsigned short f2bf(float f){
  unsigned int u = __float_as_uint(f);
  u = u + 0x7fffu + ((u >> 16) & 1u);   // RNE, inputs finite
  return (unsigned short)(u >> 16);
}
__device__ inline float exp2_hw(float x){ float r; asm("v_exp_f32 %0, %1" : "=v"(r) : "v"(x)); return r; }
__device__ inline float rcp_hw (float x){ float r; asm("v_rcp_f32 %0, %1" : "=v"(r) : "v"(x)); return r; }
__device__ inline float sigm (float x){ return rcp_hw(1.f + exp2_hw(-1.4426950408889634f*x)); }
__device__ inline float tanh_(float x){ return 1.f - 2.f*rcp_hw(1.f + exp2_hw(2.8853900817779268f*x)); }

// B-fragment for mfma_f32_16x16x32_bf16: lane needs W[row=colbase+(l&15)][kbase..kbase+7]
__device__ inline bf16x8 load_bfrag(const float* __restrict__ W, int ld, int row, int kbase, int kmax){
  bf16x8 r;
  #pragma unroll
  for(int e=0;e<8;e++){
    int k = kbase+e;
    float v = (k<kmax)? W[(long)row*ld + k] : 0.f;
    r[e] = (short)f2bf(v);
  }
  return r;
}

__global__ __launch_bounds__(THREADS, 2)
void lstm_fused(const float* __restrict__ x,
  const float* __restrict__ Wih0, const float* __restrict__ Whh0,
  const float* __restrict__ bih0, const float* __restrict__ bhh0,
  const float* __restrict__ Wih1, const float* __restrict__ Whh1,
  const float* __restrict__ bih1, const float* __restrict__ bhh1,
  const float* __restrict__ fcW,  const float* __restrict__ fcb,
  float* __restrict__ y, float* __restrict__ partial)
{
  extern __shared__ unsigned short lds[];
  unsigned short* h1s = lds;                 // [SEQ][16][H1PITCH]
  unsigned short* h2s = lds + SEQ*H1SLOT;    // [2][16][H1PITCH]

  const int tid  = threadIdx.x;
  const int lane = tid & 63;
  const int wv   = tid >> 6;      // wave 0..7
  const int lr   = lane & 15;     // A-row / B&D-col within tile
  const int lg   = lane >> 4;     // k-group / D-row-group
  const int row0 = blockIdx.x * ROWS;
  const int colw = wv*16;         // this wave's hidden-column base
  const int myc  = colw + lr;

  // ---------------- phase 1: LSTM layer 0 ----------------
  bf16x8 bh0[4][4], bi0[4];
  float  bias0[4];
  #pragma unroll
  for(int g=0; g<4; ++g){
    int gc = g*HID + myc;                       // PyTorch gate order i,f,g,o
    #pragma unroll
    for(int ks=0; ks<4; ++ks) bh0[g][ks] = load_bfrag(Whh0, HID, gc, ks*32 + lg*8, HID);
    bi0[g]   = load_bfrag(Wih0, INP, gc, lg*8, INP);   // K padded 13->32 with zeros
    bias0[g] = bih0[gc] + bhh0[gc];
  }
  float c1[4] = {0.f,0.f,0.f,0.f};
  const float* xrow = x + (long)(row0 + lr)*(SEQ*INP);

  for(int t=0; t<SEQ; ++t){
    // x_t A-fragment straight from global (tiny, L1-friendly)
    bf16x8 ax;
    #pragma unroll
    for(int e=0;e<8;e++){
      int k = lg*8 + e;
      float v = (k < INP) ? xrow[t*INP + k] : 0.f;
      ax[e] = (short)f2bf(v);
    }
    f32x4 acc[4];
    #pragma unroll
    for(int g=0;g<4;++g){
      acc[g] = (f32x4){bias0[g],bias0[g],bias0[g],bias0[g]};
      acc[g] = __builtin_amdgcn_mfma_f32_16x16x32_bf16(ax, bi0[g], acc[g], 0,0,0);
    }
    if(t>0){
      bf16x8 ah[4];
      #pragma unroll
      for(int ks=0;ks<4;++ks)
        ah[ks] = *(const bf16x8*)(h1s + (t-1)*H1SLOT + lr*H1PITCH + ks*32 + lg*8);
      #pragma unroll
      for(int g=0;g<4;++g){
        #pragma unroll
        for(int ks=0;ks<4;++ks)
          acc[g] = __builtin_amdgcn_mfma_f32_16x16x32_bf16(ah[ks], bh0[g][ks], acc[g], 0,0,0);
      }
    }
    #pragma unroll
    for(int r=0;r<4;++r){
      float iv = sigm (acc[0][r]);
      float fv = sigm (acc[1][r]);
      float gv = tanh_(acc[2][r]);
      float ov = sigm (acc[3][r]);
      c1[r] = fv*c1[r] + iv*gv;
      float hv = ov*tanh_(c1[r]);
      h1s[t*H1SLOT + (lg*4+r)*H1PITCH + myc] = f2bf(hv);
    }
    __syncthreads();
  }

  // ---------------- phase 2: LSTM layer 1 ----------------
  bf16x8 bh1[4][4], bi1[4][4];
  float  bias1[4];
  #pragma unroll
  for(int g=0; g<4; ++g){
    int gc = g*HID + myc;
    #pragma unroll
    for(int ks=0; ks<4; ++ks){
      bi1[g][ks] = load_bfrag(Wih1, HID, gc, ks*32 + lg*8, HID);
      bh1[g][ks] = load_bfrag(Whh1, HID, gc, ks*32 + lg*8, HID);
    }
    bias1[g] = bih1[gc] + bhh1[gc];
  }
  float c2[4] = {0.f,0.f,0.f,0.f};

  for(int t=0; t<SEQ; ++t){
    f32x4 acc[4];
    #pragma unroll
    for(int g=0;g<4;++g) acc[g] = (f32x4){bias1[g],bias1[g],bias1[g],bias1[g]};
    bf16x8 a1[4];
    #pragma unroll
    for(int ks=0;ks<4;++ks)
      a1[ks] = *(const bf16x8*)(h1s + t*H1SLOT + lr*H1PITCH + ks*32 + lg*8);
    #pragma unroll
    for(int g=0;g<4;++g){
      #pragma unroll
      for(int ks=0;ks<4;++ks)
        acc[g] = __builtin_amdgcn_mfma_f32_16x16x32_bf16(a1[ks], bi1[g][ks], acc[g], 0,0,0);
    }
    if(t>0){
      bf16x8 a2[4];
      #pragma unroll
      for(int ks=0;ks<4;++ks)
        a2[ks] = *(const bf16x8*)(h2s + ((t-1)&1)*H1SLOT + lr*H1PITCH + ks*32 + lg*8);
      #pragma unroll
      for(int g=0;g<4;++g){
        #pragma unroll
        for(int ks=0;ks<4;++ks)
          acc[g] = __builtin_amdgcn_mfma_f32_16x16x32_bf16(a2[ks], bh1[g][ks], acc[g], 0,0,0);
      }
    }
    #pragma unroll
    for(int r=0;r<4;++r){
      float iv = sigm (acc[0][r]);
      float fv = sigm (acc[1][r]);
      float gv = tanh_(acc[2][r]);
      float ov = sigm (acc[3][r]);
      c2[r] = fv*c2[r] + iv*gv;
      float hv = ov*tanh_(c2[r]);
      h2s[(t&1)*H1SLOT + (lg*4+r)*H1PITCH + myc] = f2bf(hv);
    }
    __syncthreads();
  }

  // ---------------- FC epilogue: y = h2_last @ fcW^T + fcb ----------------
  bf16x8 bfc[4];
  #pragma unroll
  for(int ks=0;ks<4;++ks) bfc[ks] = load_bfrag(fcW, HID, myc, ks*32 + lg*8, HID);
  f32x4 accy = (f32x4){fcb[myc],fcb[myc],fcb[myc],fcb[myc]};
  #pragma unroll
  for(int ks=0;ks<4;++ks){
    bf16x8 a2 = *(const bf16x8*)(h2s + 1*H1SLOT + lr*H1PITCH + ks*32 + lg*8); // (SEQ-1)&1 == 1
    accy = __builtin_amdgcn_mfma_f32_16x16x32_bf16(a2, bfc[ks], accy, 0,0,0);
  }
  float s=0.f, sq=0.f;
  #pragma unroll
  for(int r=0;r<4;++r){
    float v = accy[r];
    y[(long)(row0 + lg*4 + r)*HID + myc] = v;
    s += v; sq += v*v;
  }
  // lanes {l, l+16, l+32, l+48} hold the same column, different row-groups
  s  += __shfl_xor(s , 16, 64);  s  += __shfl_xor(s , 32, 64);
  sq += __shfl_xor(sq, 16, 64);  sq += __shfl_xor(sq, 32, 64);
  if(lg==0){
    partial[(long)myc      *NBLK + blockIdx.x] = s;
    partial[(long)(HID+myc)*NBLK + blockIdx.x] = sq;
  }
}

// ---------------- BN reduce: one block per column ----------------
__global__ void bn_reduce(const float* __restrict__ partial, float* __restrict__ mv){
  int c = blockIdx.x;
  float s=0.f, sq=0.f;
  for(int i=threadIdx.x; i<NBLK; i+=256){
    s  += partial[(long)c      *NBLK + i];
    sq += partial[(long)(HID+c)*NBLK + i];
  }
  #pragma unroll
  for(int m=32;m>=1;m>>=1){ s += __shfl_xor(s,m,64); sq += __shfl_xor(sq,m,64); }
  __shared__ float rs[4], rq[4];
  int w = threadIdx.x>>6;
  if((threadIdx.x&63)==0){ rs[w]=s; rq[w]=sq; }
  __syncthreads();
  if(threadIdx.x==0){
    s  = rs[0]+rs[1]+rs[2]+rs[3];
    sq = rq[0]+rq[1]+rq[2]+rq[3];
    float mean = s / (float)BATCH;
    float var  = sq / (float)BATCH - mean*mean;
    mv[c]     = mean;
    mv[HID+c] = rsqrtf(var + 1e-5f);
  }
}

// ---------------- BN apply: in-place normalize d_out ----------------
__global__ void bn_apply(float* __restrict__ y, const float* __restrict__ mv,
                         const float* __restrict__ gamma, const float* __restrict__ beta){
  long idx = ((long)blockIdx.x*256 + threadIdx.x)*4;
  int c = (int)(idx & (HID-1));
  float4 v = *reinterpret_cast<float4*>(y+idx);
  v.x = gamma[c+0]*(v.x - mv[c+0])*mv[HID+c+0] + beta[c+0];
  v.y = gamma[c+1]*(v.y - mv[c+1])*mv[HID+c+1] + beta[c+1];
  v.z = gamma[c+2]*(v.z - mv[c+2])*mv[HID+c+2] + beta[c+2];
  v.w = gamma[c+3]*(v.w - mv[c+3])*mv[HID+c+3] + beta[c+3];
  *reinterpret_cast<float4*>(y+idx) = v;
}

extern "C" void kernel_launch(void* const* d_in, const int* in_sizes, int n_in,
                              void* d_out, int out_size, void* d_ws, size_t ws_size,
                              hipStream_t stream){
  const float* x    = (const float*)d_in[0];
  const float* Wih0 = (const float*)d_in[1];
  const float* Whh0 = (const float*)d_in[2];
  const float* bih0 = (const float*)d_in[3];
  const float* bhh0 = (const float*)d_in[4];
  const float* Wih1 = (const float*)d_in[5];
  const float* Whh1 = (const float*)d_in[6];
  const float* bih1 = (const float*)d_in[7];
  const float* bhh1 = (const float*)d_in[8];
  const float* fcW  = (const float*)d_in[9];
  const float* fcb  = (const float*)d_in[10];
  const float* gamma= (const float*)d_in[11];
  const float* beta = (const float*)d_in[12];

  float* y       = (float*)d_out;
  float* partial = (float*)d_ws;                       // 2*HID*NBLK f32 = 2 MB
  float* mv      = partial + (long)2*HID*NBLK;         // 256 f32

  hipFuncSetAttribute((const void*)lstm_fused,
                      hipFuncAttributeMaxDynamicSharedMemorySize, LDS_BYTES);

  lstm_fused<<<NBLK, THREADS, LDS_BYTES, stream>>>(
      x, Wih0, Whh0, bih0, bhh0, Wih1, Whh1, bih1, bhh1, fcW, fcb, y, partial);
  bn_reduce<<<HID, 256, 0, stream>>>(partial, mv);
  bn_apply<<<(BATCH*HID)/(256*4), 256, 0, stream>>>(y, mv, gamma, beta);
}